// Round 3
// baseline (2156.332 us; speedup 1.0000x reference)
//
#include <hip/hip_runtime.h>

#define BATCH   512
#define G       4                    // batches per block (ILP group)
#define NBLK    (BATCH / G)          // 128 blocks -> 1 block/CU, 1 wave/SIMD
#define TSTEPS  3600
#define H       64
#define XCHUNK  8
#define NCHUNK  (TSTEPS / XCHUNK)    // 450
#define CLASSES 5

typedef _Float16 half8 __attribute__((ext_vector_type(8)));
typedef float    f32x4 __attribute__((ext_vector_type(4)));

#define L2E 1.44269504088896f
#define S_N (2.0f * L2E)

__device__ __forceinline__ half8 bc_h8(uint4 v) { return __builtin_bit_cast(half8, v); }

// FOUR WAVES, FOUR BATCHES per block. R2 post-mortem fixed the HW model:
// one 16x16x32 MFMA = ~16 cyc/SIMD pipe, so R2's step = barrier 45 +
// ds_read 140 + MFMA 96 + tail 110 + slop ~ 536 cyc, ALL serial, GPU idle.
// Cross-block concurrency can't shorten a chain; in-wave ILP can: each
// block advances G=4 independent batches per barrier segment. The fixed
// latencies (barrier, read window, tail epilogue) amortize /4 while the
// 4 batches' 24 MFMAs stream through a PRIVATE SIMD pipe (128 blocks ->
// 1 wave/SIMD, no sibling contention). Also: ir/iz folded into MFMA C
// operands (projections computed one step ahead -> off-path), z tiles
// issued last (shortest post-MFMA chain binds), tanh tail via
// nn=fma(-2,u,1)/s=fma(2,u,h-1), all-64-lane h-store into 4 bank-staggered
// copies (160B stride; copy q feeds q-group's A-octet read) - no exec mask.
__global__ __launch_bounds__(256, 1) void gru_mfma_kernel(
    const float* __restrict__ x,      // [B, T, 1]
    const float* __restrict__ w_ih,   // [192, 1]
    const float* __restrict__ w_hh,   // [192, 64]
    const float* __restrict__ b_ih,   // [192]
    const float* __restrict__ b_hh,   // [192]
    const float* __restrict__ w_head, // [5, 64]
    const float* __restrict__ b_head, // [5]
    float* __restrict__ out)          // [B, 5]
{
    // per-batch region: 2 parities x 4 copies x 80 f16 (160B stride) = 1280B
    __shared__ __align__(16) _Float16 hbuf[G * 2 * 4 * 80];
    __shared__ float hf[H];

    const int tid  = threadIdx.x;
    const int w    = tid >> 6;       // wave id: owns tile w of each gate
    const int lane = tid & 63;
    const int q    = lane >> 4;      // A k-octet selector
    const int col  = lane & 15;      // tile column
    const int b0   = blockIdx.x * G;
    const int i    = 16 * w + col;   // this lane's hidden index

    // --- B fragments: gate tiles {w, 4+w, 8+w}, f16, exp2-pre-scaled.
    half8 wR[2], wZ[2], wN[2];
#pragma unroll
    for (int c = 0; c < 2; ++c) {
        const float* pr = w_hh + (16 * w       + col) * H + 32 * c + 8 * q;
        const float* pz = w_hh + (16 * (4 + w) + col) * H + 32 * c + 8 * q;
        const float* pn = w_hh + (16 * (8 + w) + col) * H + 32 * c + 8 * q;
        half8 fr, fz, fn;
#pragma unroll
        for (int j = 0; j < 8; ++j) {
            fr[j] = (_Float16)(-L2E * pr[j]);
            fz[j] = (_Float16)(-L2E * pz[j]);
            fn[j] = (_Float16)( S_N * pn[j]);
        }
        wR[c] = fr; wZ[c] = fz; wN[c] = fn;
    }

    const float bn = S_N * b_hh[2 * H + i];
    const f32x4 Cn = {bn, bn, bn, bn};       // n bias rides the MFMA C chain
    const f32x4 Z  = {0.f, 0.f, 0.f, 0.f};

    const float wih_r = -L2E * w_ih[i];
    const float wih_z = -L2E * w_ih[H + i];
    const float wih_n =  S_N * w_ih[2 * H + i];
    const float bsr = -L2E * (b_ih[i] + b_hh[i]);
    const float bsz = -L2E * (b_ih[H + i] + b_hh[H + i]);
    const float bin =  S_N * b_ih[2 * H + i];

    char* hb = (char*)hbuf;
    const int woff  = q * 160 + i * 2;   // write slot: copy q, value i
    const int roff0 = 176 * q;           // A0: copy q, h[8q..8q+7]
    const int roff1 = 176 * q + 64;      // A1: copy q, h[32+8q..+7]

#pragma unroll
    for (int g = 0; g < G; ++g)          // h0 = 0, parity-0 buffers
        *(_Float16*)(hb + g * 1280 + woff) = (_Float16)0.0f;
    __syncthreads();

    float hreg[G], hm1[G], irc[G], izc[G], inc[G], vxc[G], vxn[G];
#pragma unroll
    for (int g = 0; g < G; ++g) {
        hreg[g] = 0.0f; hm1[g] = -1.0f;
        vxc[g] = x[(size_t)(b0 + g) * TSTEPS + (col & 7)];
        const float xt0 = __builtin_bit_cast(float,
            __builtin_amdgcn_readlane(__builtin_bit_cast(int, vxc[g]), 0));
        irc[g] = fmaf(xt0, wih_r, bsr);
        izc[g] = fmaf(xt0, wih_z, bsz);
        inc[g] = fmaf(xt0, wih_n, bin);
    }

    for (int tc = 0; tc < NCHUNK; ++tc) {
        const int nb = (tc + 1 < NCHUNK) ? (tc + 1) * XCHUNK : 0;
#pragma unroll
        for (int g = 0; g < G; ++g)
            vxn[g] = x[(size_t)(b0 + g) * TSTEPS + nb + (col & 7)];

#pragma unroll
        for (int tt = 0; tt < XCHUNK; ++tt) {
            const int pr = (tt & 1) * 640;         // read parity base
            const int pw = ((tt & 1) ^ 1) * 640;   // write parity base

            // grouped read issue: first batch's latency exposed, rest hidden
            uint4 a0u[G], a1u[G];
#pragma unroll
            for (int g = 0; g < G; ++g) {
                a0u[g] = *(const uint4*)(hb + g * 1280 + pr + roff0);
                a1u[g] = *(const uint4*)(hb + g * 1280 + pr + roff1);
            }

            f32x4 r0[G], r1[G], n0[G], n1[G], z0[G], z1[G];
#pragma unroll
            for (int g = 0; g < G; ++g) {
                const half8 A0 = bc_h8(a0u[g]);
                const half8 A1 = bc_h8(a1u[g]);
                const f32x4 Cr = {irc[g], irc[g], irc[g], irc[g]};
                const f32x4 Cz = {izc[g], izc[g], izc[g], izc[g]};
                // r first (heads the tail), z last (shortest post-chain)
                r0[g] = __builtin_amdgcn_mfma_f32_16x16x32_f16(A0, wR[0], Cr, 0, 0, 0);
                r1[g] = __builtin_amdgcn_mfma_f32_16x16x32_f16(A1, wR[1], Z,  0, 0, 0);
                n0[g] = __builtin_amdgcn_mfma_f32_16x16x32_f16(A0, wN[0], Cn, 0, 0, 0);
                n1[g] = __builtin_amdgcn_mfma_f32_16x16x32_f16(A1, wN[1], Z,  0, 0, 0);
                z0[g] = __builtin_amdgcn_mfma_f32_16x16x32_f16(A0, wZ[0], Cz, 0, 0, 0);
                z1[g] = __builtin_amdgcn_mfma_f32_16x16x32_f16(A1, wZ[1], Z,  0, 0, 0);
            }

            // next-step input projections: fully off the critical path
            float irn[G], izn[G], inn[G];
#pragma unroll
            for (int g = 0; g < G; ++g) {
                const float vxs = (tt == XCHUNK - 1) ? vxn[g] : vxc[g];
                const float xtn = __builtin_bit_cast(float,
                    __builtin_amdgcn_readlane(__builtin_bit_cast(int, vxs),
                                              (tt + 1) & (XCHUNK - 1)));
                irn[g] = fmaf(xtn, wih_r, bsr);
                izn[g] = fmaf(xtn, wih_z, bsz);
                inn[g] = fmaf(xtn, wih_n, bin);
            }

#pragma unroll
            for (int g = 0; g < G; ++g) {
                const float er = __builtin_amdgcn_exp2f(r0[g][0] + r1[g][0]);
                const float rg = __builtin_amdgcn_rcpf(1.0f + er);
                const float ev = __builtin_amdgcn_exp2f(
                                     fmaf(rg, n0[g][0] + n1[g][0], inc[g]));
                const float u  = __builtin_amdgcn_rcpf(ev + 1.0f);
                const float nn = fmaf(-2.0f, u, 1.0f);      // tanh
                const float s  = fmaf(2.0f, u, hm1[g]);     // h-1+2u
                const float ez = __builtin_amdgcn_exp2f(z0[g][0] + z1[g][0]);
                const float zg = __builtin_amdgcn_rcpf(1.0f + ez);
                hreg[g] = fmaf(zg, s, nn);   // zh + (1-z)tanh
                hm1[g]  = hreg[g] - 1.0f;
                *(_Float16*)(hb + g * 1280 + pw + woff) = (_Float16)hreg[g];
            }
            __syncthreads();

#pragma unroll
            for (int g = 0; g < G; ++g) {
                irc[g] = irn[g]; izc[g] = izn[g]; inc[g] = inn[g];
            }
        }
#pragma unroll
        for (int g = 0; g < G; ++g) vxc[g] = vxn[g];
    }

    // ---- head: out[b0+g][c] = w_head[c,:] . h_g + b_head[c] ----
#pragma unroll
    for (int g = 0; g < G; ++g) {
        if (lane < 16) hf[i] = hreg[g];
        __syncthreads();
        if (w == 0) {
            const float hv = hf[lane];
#pragma unroll
            for (int cc = 0; cc < CLASSES; ++cc) {
                float v = hv * w_head[cc * H + lane];
#pragma unroll
                for (int off = 32; off > 0; off >>= 1)
                    v += __shfl_down(v, off, 64);
                if (lane == 0) out[(b0 + g) * CLASSES + cc] = v + b_head[cc];
            }
        }
        __syncthreads();
    }
}

extern "C" void kernel_launch(void* const* d_in, const int* in_sizes, int n_in,
                              void* d_out, int out_size, void* d_ws, size_t ws_size,
                              hipStream_t stream) {
    const float* x      = (const float*)d_in[0];
    const float* w_ih   = (const float*)d_in[1];
    const float* w_hh   = (const float*)d_in[2];
    const float* b_ih   = (const float*)d_in[3];
    const float* b_hh   = (const float*)d_in[4];
    const float* w_head = (const float*)d_in[5];
    const float* b_head = (const float*)d_in[6];
    float* out = (float*)d_out;

    gru_mfma_kernel<<<NBLK, 256, 0, stream>>>(x, w_ih, w_hh, b_ih, b_hh,
                                              w_head, b_head, out);
}

// Round 4
// 722.945 us; speedup vs baseline: 2.9827x; 2.9827x over previous
//
#include <hip/hip_runtime.h>

#define BATCH   512
#define GB      4                    // batches per block, carried on MFMA D-rows
#define NBLK    (BATCH / GB)         // 128 blocks, 4 waves each -> 1 wave/SIMD
#define TSTEPS  3600
#define H       64
#define XCHUNK  16
#define NCHUNK  (TSTEPS / XCHUNK)    // 225
#define CLASSES 5

typedef _Float16 half8 __attribute__((ext_vector_type(8)));
typedef float    f32x4 __attribute__((ext_vector_type(4)));

#define L2E 1.44269504088896f
#define S_N (2.0f * L2E)

__device__ __forceinline__ half8 bc_h8(uint4 v) { return __builtin_bit_cast(half8, v); }

// BATCHES ON THE MFMA ROWS. R3 lesson: amortizing latency by multiplying
// per-wave work (in-wave G-unroll) serializes on the wave's in-order issue
// (536 -> 1437 cyc/step). This kernel amortizes on the UNUSED m-dimension
// instead: A[m][k] = h_{m>>2}[k] (4 batches x 4 replica rows), so the SAME
// 6 MFMAs per wave serve 4 batches, and each lane's tail is ONE cell
// (batch q=lane>>4, hidden i=16w+col) -- per-wave instruction count is
// R2's, per-batch cost /4. 128 blocks -> 1 wave/SIMD: no sibling
// contention; the step runs at the bare chain (~read 140 + mfma ~100 +
// tail ~100 + barrier ~60). ir/iz ride the MFMA C operand: only row 4q /
// reg 0 is ever read, so C[0]=proj is a single v_mov (C[1..3] stay 0).
// x for (batch, step) lives distributed across lanes; one off-path
// ds_bpermute per step fetches next step's x. LDS: h as [parity][batch][k]
// f16, batch stride 160B -> A-reads 2-way bank aliased (free, m136),
// h-writes conflict-free.
__global__ __launch_bounds__(256, 1) void gru_mfma_kernel(
    const float* __restrict__ x,      // [B, T, 1]
    const float* __restrict__ w_ih,   // [192, 1]
    const float* __restrict__ w_hh,   // [192, 64]
    const float* __restrict__ b_ih,   // [192]
    const float* __restrict__ b_hh,   // [192]
    const float* __restrict__ w_head, // [5, 64]
    const float* __restrict__ b_head, // [5]
    float* __restrict__ out)          // [B, 5]
{
    // [parity][batch*80 f16]: batch stride 160B, parity stride 640B
    __shared__ __align__(16) _Float16 hB[2][GB * 80];
    __shared__ float hf[GB][H];

    const int tid  = threadIdx.x;
    const int w    = tid >> 6;        // wave id: gate tiles {w, 4+w, 8+w}
    const int lane = tid & 63;
    const int q    = lane >> 4;       // this lane's BATCH (D rows 4q..4q+3)
    const int col  = lane & 15;       // tile column
    const int b0   = blockIdx.x * GB;
    const int i    = 16 * w + col;    // this lane's hidden index

    // --- B fragments: gate tiles {w, 4+w, 8+w}, f16, exp2-pre-scaled.
    // B[k=8q'+j][n=col] = sc * W[16T+col][32c+8q'+j], q' = lane>>4
    half8 wR[2], wZ[2], wN[2];
#pragma unroll
    for (int c = 0; c < 2; ++c) {
        const float* pr = w_hh + (16 * w       + col) * H + 32 * c + 8 * q;
        const float* pz = w_hh + (16 * (4 + w) + col) * H + 32 * c + 8 * q;
        const float* pn = w_hh + (16 * (8 + w) + col) * H + 32 * c + 8 * q;
        half8 fr, fz, fn;
#pragma unroll
        for (int j = 0; j < 8; ++j) {
            fr[j] = (_Float16)(-L2E * pr[j]);
            fz[j] = (_Float16)(-L2E * pz[j]);
            fn[j] = (_Float16)( S_N * pn[j]);
        }
        wR[c] = fr; wZ[c] = fz; wN[c] = fn;
    }

    const float bn = S_N * b_hh[2 * H + i];
    f32x4 Cn = {bn, bn, bn, bn};     // n bias rides the MFMA C chain
    const f32x4 Z = {0.f, 0.f, 0.f, 0.f};
    f32x4 Cr = Z, Cz = Z;            // per-step: only element 0 updated

    const float wih_r = -L2E * w_ih[i];
    const float wih_z = -L2E * w_ih[H + i];
    const float wih_n =  S_N * w_ih[2 * H + i];
    const float bsr = -L2E * (b_ih[i] + b_hh[i]);
    const float bsz = -L2E * (b_ih[H + i] + b_hh[H + i]);
    const float bin =  S_N * b_ih[2 * H + i];

    // LDS byte offsets (within a parity region)
    char* hbase = (char*)&hB[0][0];
    const int rdA0 = (col >> 2) * 160 + q * 16;  // A0: batch col>>2, k=8q..8q+7
    const int rdA1 = rdA0 + 64;                  // A1: k=32+8q..32+8q+7
    const int wrH  = q * 160 + i * 2;            // write: batch q, value i

    *(_Float16*)(hbase + wrH) = (_Float16)0.0f;  // h0 = 0 (parity 0)
    __syncthreads();

    // x staging: lane (q,col) holds x[batch q][chunk, step col]
    const float* xq = x + (size_t)(b0 + q) * TSTEPS;
    float vx = xq[col];
    const int pbase = 64 * q;        // bpermute byte base: lane 16q

    // proj for step 0
    float xt0 = __builtin_bit_cast(float,
        __builtin_amdgcn_ds_bpermute(pbase, __builtin_bit_cast(int, vx)));
    float irc = fmaf(xt0, wih_r, bsr);
    float izc = fmaf(xt0, wih_z, bsz);
    float inc = fmaf(xt0, wih_n, bin);

    float h_reg = 0.0f, hm1 = -1.0f;

    for (int tc = 0; tc < NCHUNK; ++tc) {
        const int nb = (tc + 1 < NCHUNK) ? (tc + 1) * XCHUNK : 0;
        const float vxn = xq[nb + col];

#pragma unroll
        for (int tt = 0; tt < XCHUNK; ++tt) {
            const int pr_ = (tt & 1) * 640;          // read parity base
            const int pw_ = ((tt & 1) ^ 1) * 640;    // write parity base

            const uint4 a0 = *(const uint4*)(hbase + pr_ + rdA0);
            const uint4 a1 = *(const uint4*)(hbase + pr_ + rdA1);

            // next step's x (off the critical path; in-wave bpermute)
            const float xsrc = (tt == XCHUNK - 1) ? vxn : vx;
            const float xtn = __builtin_bit_cast(float,
                __builtin_amdgcn_ds_bpermute(pbase + 4 * ((tt + 1) & 15),
                                             __builtin_bit_cast(int, xsrc)));

            Cr[0] = irc;             // only row 4q / reg 0 is consumed
            Cz[0] = izc;

            const half8 A0 = bc_h8(a0);
            const half8 A1 = bc_h8(a1);
            f32x4 dr, dn, dz;
            dr = __builtin_amdgcn_mfma_f32_16x16x32_f16(A0, wR[0], Cr, 0, 0, 0);
            dr = __builtin_amdgcn_mfma_f32_16x16x32_f16(A1, wR[1], dr, 0, 0, 0);
            dn = __builtin_amdgcn_mfma_f32_16x16x32_f16(A0, wN[0], Cn, 0, 0, 0);
            dn = __builtin_amdgcn_mfma_f32_16x16x32_f16(A1, wN[1], dn, 0, 0, 0);
            dz = __builtin_amdgcn_mfma_f32_16x16x32_f16(A0, wZ[0], Cz, 0, 0, 0);
            dz = __builtin_amdgcn_mfma_f32_16x16x32_f16(A1, wZ[1], dz, 0, 0, 0);

            // tail: one cell per lane (batch q, hidden i)
            const float er = __builtin_amdgcn_exp2f(dr[0]);
            const float r  = __builtin_amdgcn_rcpf(1.0f + er);
            const float ev = __builtin_amdgcn_exp2f(fmaf(r, dn[0], inc));
            const float u  = __builtin_amdgcn_rcpf(ev + 1.0f);
            const float nn = fmaf(-2.0f, u, 1.0f);      // tanh
            const float s  = fmaf(2.0f, u, hm1);        // h-1+2u
            const float ez = __builtin_amdgcn_exp2f(dz[0]);
            const float zg = __builtin_amdgcn_rcpf(1.0f + ez);
            h_reg = fmaf(zg, s, nn);                    // zh + (1-z)n
            hm1   = h_reg - 1.0f;

            // next step's projections (off-path; reads THIS step's xtn)
            irc = fmaf(xtn, wih_r, bsr);
            izc = fmaf(xtn, wih_z, bsz);
            inc = fmaf(xtn, wih_n, bin);

            *(_Float16*)(hbase + pw_ + wrH) = (_Float16)h_reg;
            __syncthreads();
        }
        vx = vxn;
    }

    // ---- head: wave w reduces batch w ----
    hf[q][i] = h_reg;                 // 256 threads cover 4x64 slots
    __syncthreads();
    {
        const float hv = hf[w][lane];
#pragma unroll
        for (int cc = 0; cc < CLASSES; ++cc) {
            float v = hv * w_head[cc * H + lane];
#pragma unroll
            for (int off = 32; off > 0; off >>= 1)
                v += __shfl_down(v, off, 64);
            if (lane == 0) out[(b0 + w) * CLASSES + cc] = v + b_head[cc];
        }
    }
}

extern "C" void kernel_launch(void* const* d_in, const int* in_sizes, int n_in,
                              void* d_out, int out_size, void* d_ws, size_t ws_size,
                              hipStream_t stream) {
    const float* x      = (const float*)d_in[0];
    const float* w_ih   = (const float*)d_in[1];
    const float* w_hh   = (const float*)d_in[2];
    const float* b_ih   = (const float*)d_in[3];
    const float* b_hh   = (const float*)d_in[4];
    const float* w_head = (const float*)d_in[5];
    const float* b_head = (const float*)d_in[6];
    float* out = (float*)d_out;

    gru_mfma_kernel<<<NBLK, 256, 0, stream>>>(x, w_ih, w_hh, b_ih, b_hh,
                                              w_head, b_head, out);
}